// Round 13
// baseline (58.869 us; speedup 1.0000x reference)
//
#include <hip/hip_runtime.h>

#define FIN 96
#define HID 64
#define NCLS 5
#define BSH 6                 // 64 nodes per coarse bucket
#define BNODES 64
#define MAXNB 1024            // >= NB = ceil(50000/64) = 782
#define CAPSH 11              // 2048-slot sortedSrc window per bucket
#define EPB 4096              // edges per bin block
#define MAXRUNS 256           // >= nbb = ceil(800000/4096) = 196
#define G1R 64                // gemm1 rows per block
#define SXP 100               // padded sX stride (floats)

// ---------------- threefry2x32 (JAX partitionable path, verified r3-r12) ---
__device__ __forceinline__ unsigned rotl32(unsigned x, int d) {
    return (x << d) | (x >> (32 - d));
}

__device__ __forceinline__ void threefry2x32(unsigned k0, unsigned k1,
                                             unsigned c0, unsigned c1,
                                             unsigned& o0, unsigned& o1) {
    unsigned ks2 = k0 ^ k1 ^ 0x1BD11BDAu;
    unsigned x0 = c0 + k0, x1 = c1 + k1;
#define RND(r) { x0 += x1; x1 = rotl32(x1, r); x1 ^= x0; }
#define G0 RND(13) RND(15) RND(26) RND(6)
#define G1 RND(17) RND(29) RND(16) RND(24)
    G0; x0 += k1;  x1 += ks2 + 1u;
    G1; x0 += ks2; x1 += k0 + 2u;
    G0; x0 += k0;  x1 += k1 + 3u;
    G1; x0 += k1;  x1 += ks2 + 4u;
    G0; x0 += ks2; x1 += k0 + 5u;
#undef G0
#undef G1
#undef RND
    o0 = x0; o1 = x1;
}

__device__ __forceinline__ float drop_mask_mul(unsigned t) {
    unsigned o0, o1;
    threefry2x32(0u, 1u, 0u, t, o0, o1);
    unsigned bits = o0 ^ o1;
    float u = __uint_as_float((bits >> 9) | 0x3f800000u) - 1.0f;
    return (u < 0.4f) ? 2.5f : 0.0f;   // 1/(1-0.6)
}

__device__ __forceinline__ unsigned short f2bf(float f) {
    unsigned u = __float_as_uint(f);
    unsigned r = 0x7fffu + ((u >> 16) & 1u);
    return (unsigned short)((u + r) >> 16);
}

__device__ __forceinline__ float bflo(unsigned u) { return __uint_as_float(u << 16); }
__device__ __forceinline__ float bfhi(unsigned u) { return __uint_as_float(u & 0xffff0000u); }

// single-wave exclusive scan of per-lane totals (lanes 0..63, no barriers)
__device__ __forceinline__ int wave_excl_scan(int v, int lane) {
    int inc = v;
    #pragma unroll
    for (int off = 1; off < 64; off <<= 1) {
        int u = __shfl_up(inc, off, 64);
        if (lane >= off) inc += u;
    }
    return inc - v;
}

// ====== kernel 1: bin blocks [0,nbb) || gemm1 blocks [nbb, nbb+g1b) ========
__global__ __launch_bounds__(256) void gemm1_bin_kernel(
        const float* __restrict__ x, const float* __restrict__ W,
        unsigned short* __restrict__ t1b,
        const int* __restrict__ src, const int* __restrict__ dst,
        int* __restrict__ cntMat, int* __restrict__ startMat,
        unsigned* __restrict__ bin, int N, int E, int NB, int nbb) {
    __shared__ __align__(16) char smem[50176];
    if ((int)blockIdx.x < nbb) {
        // ---------------- bin path: dense per-block bucket grouping --------
        int* hist_s = (int*)smem;            // [MAXNB]
        int* cur_s  = hist_s + MAXNB;        // [MAXNB]
        int blk = blockIdx.x;
        int e0 = blk * EPB;
        for (int k = threadIdx.x; k < NB; k += 256) hist_s[k] = 0;
        __syncthreads();
        int ss[16], dd[16];
        int base = e0 + threadIdx.x * 16;
        #pragma unroll
        for (int q = 0; q < 4; ++q) {
            int b4 = base + q * 4;
            if (b4 + 3 < E) {
                int4 s4 = *(const int4*)&src[b4];
                int4 d4 = *(const int4*)&dst[b4];
                ss[q*4+0]=s4.x; ss[q*4+1]=s4.y; ss[q*4+2]=s4.z; ss[q*4+3]=s4.w;
                dd[q*4+0]=d4.x; dd[q*4+1]=d4.y; dd[q*4+2]=d4.z; dd[q*4+3]=d4.w;
            } else {
                #pragma unroll
                for (int j = 0; j < 4; ++j) {
                    ss[q*4+j] = (b4+j < E) ? src[b4+j] : 0;
                    dd[q*4+j] = (b4+j < E) ? dst[b4+j] : -1;
                }
            }
        }
        #pragma unroll
        for (int j = 0; j < 16; ++j)
            if (dd[j] >= 0) atomicAdd(&hist_s[dd[j] >> BSH], 1);
        __syncthreads();
        // single-wave exclusive scan over NB buckets (13 entries/lane)
        if (threadIdx.x < 64) {
            int lane = threadIdx.x;
            int h[13]; int t = 0;
            #pragma unroll
            for (int j = 0; j < 13; ++j) {
                int k = lane * 13 + j;
                h[j] = (k < NB) ? hist_s[k] : 0;
                t += h[j];
            }
            int excl = wave_excl_scan(t, lane);
            #pragma unroll
            for (int j = 0; j < 13; ++j) {
                int k = lane * 13 + j;
                if (k < NB) {
                    cur_s[k] = excl;
                    cntMat[blk * NB + k]   = h[j];            // block-major
                    startMat[blk * NB + k] = e0 + excl;       // absolute
                }
                excl += h[j];
            }
        }
        __syncthreads();
        #pragma unroll
        for (int j = 0; j < 16; ++j) {
            int d = dd[j];
            if (d < 0) continue;
            int k = d >> BSH;
            int p = e0 + atomicAdd(&cur_s[k], 1);
            bin[p] = ((unsigned)(d & (BNODES - 1)) << 16) | (unsigned)ss[j];
        }
    } else {
        // ---------------- gemm1 path (r10-r12 verified, 4x4 reg tiling) ----
        float* sX = (float*)smem;                 // 64*100*4 = 25600 B
        float* sW = (float*)(smem + 25600);       // 96*64*4  = 24576 B
        int row0 = ((int)blockIdx.x - nbb) * G1R;
        for (int i = threadIdx.x * 4; i < FIN * HID; i += 1024)
            *(float4*)&sW[i] = *(const float4*)&W[i];
        for (int i = threadIdx.x; i < G1R * (FIN / 4); i += 256) {
            int r = i / (FIN / 4), m = i % (FIN / 4);
            int gr = row0 + r;
            float4 v = make_float4(0.f, 0.f, 0.f, 0.f);
            if (gr < N) v = *(const float4*)&x[gr * FIN + m * 4];
            *(float4*)&sX[r * SXP + m * 4] = v;
        }
        __syncthreads();
        int tc = threadIdx.x & 15;
        int tr = threadIdx.x >> 4;
        float acc[4][4] = {};
        const float* xb = &sX[tr * 4 * SXP];
        for (int k = 0; k < FIN; ++k) {
            float4 w = *(const float4*)&sW[k * HID + tc * 4];
            #pragma unroll
            for (int j = 0; j < 4; ++j) {
                float xv = xb[j * SXP + k];
                acc[j][0] += xv * w.x;
                acc[j][1] += xv * w.y;
                acc[j][2] += xv * w.z;
                acc[j][3] += xv * w.w;
            }
        }
        #pragma unroll
        for (int j = 0; j < 4; ++j) {
            int gr = row0 + tr * 4 + j;
            if (gr < N) {
                ushort4 o;
                o.x = f2bf(acc[j][0]); o.y = f2bf(acc[j][1]);
                o.z = f2bf(acc[j][2]); o.w = f2bf(acc[j][3]);
                *(ushort4*)&t1b[gr * HID + tc * 4] = o;
            }
        }
    }
}

// ====== kernel 2: per-bucket counting sort (LDS) + agg1 + gemm2 ===========
// 512 threads; agg phase = 64 nodes x 8 lanes exactly.
__global__ __launch_bounds__(512) void sortagg_kernel(
        const int* __restrict__ cntMat, const int* __restrict__ startMat,
        const unsigned* __restrict__ bin, const uint4* __restrict__ t1v,
        const float* __restrict__ b1, const float* __restrict__ W2,
        int* __restrict__ offset, int* __restrict__ count,
        unsigned short* __restrict__ sortedSrc, float* __restrict__ t2p,
        int N, int nbb, int NB) {
    __shared__ int cntRow[MAXRUNS];
    __shared__ int startRow[MAXRUNS];
    __shared__ int runOff[MAXRUNS + 1];
    __shared__ int cnt_s[BNODES], off_s[BNODES], cur_s[BNODES];
    __shared__ unsigned raw_s[2048];
    __shared__ __align__(16) unsigned short list_s[2048];
    __shared__ float sW2[HID * NCLS];
    __shared__ float sB1[HID];
    int b = blockIdx.x, tid = threadIdx.x;

    for (int i = tid; i < HID * NCLS; i += 512) sW2[i] = W2[i];
    if (tid < HID) sB1[tid] = b1[tid];
    if (tid < nbb) {
        cntRow[tid]   = cntMat[tid * NB + b];     // block-major source
        startRow[tid] = startMat[tid * NB + b];
    }
    if (tid < BNODES) cnt_s[tid] = 0;
    __syncthreads();                                   // sync 1
    // single-wave exclusive scan -> runOff[0..nbb] (4 entries/lane)
    if (tid < 64) {
        int c[4]; int t = 0;
        #pragma unroll
        for (int j = 0; j < 4; ++j) {
            int r = tid * 4 + j;
            c[j] = (r < nbb) ? cntRow[r] : 0;
            t += c[j];
        }
        int excl = wave_excl_scan(t, tid);
        #pragma unroll
        for (int j = 0; j < 4; ++j) {
            runOff[tid * 4 + j] = excl;
            excl += c[j];
        }
        if (tid == 63) runOff[256] = excl;             // unused guard
    }
    __syncthreads();                                   // sync 2
    int T = runOff[nbb];
    if (T > 2048) T = 2048;                            // safety (never hit)

    // pass 1: gather recs -> raw_s, node histogram
    for (int i = tid; i < T; i += 512) {
        int lo = 0, hi = nbb;
        while (hi - lo > 1) {
            int mid = (lo + hi) >> 1;
            if (runOff[mid] <= i) lo = mid; else hi = mid;
        }
        unsigned rec = bin[startRow[lo] + (i - runOff[lo])];
        raw_s[i] = rec;
        atomicAdd(&cnt_s[rec >> 16], 1);
    }
    __syncthreads();                                   // sync 3
    // single-wave pad4 exclusive scan over 64 node counts (1 entry/lane)
    if (tid < 64) {
        int c0 = cnt_s[tid];
        int p0 = (c0 + 3) & ~3;
        int excl = wave_excl_scan(p0, tid);
        off_s[tid] = excl;
        cur_s[tid] = excl;
        int node = (b << BSH) + tid;
        if (node < N) {
            offset[node] = (b << CAPSH) + excl;
            count[node]  = c0;
        }
    }
    __syncthreads();                                   // sync 4
    // pass 2: scatter into node-grouped list (LDS) + global sortedSrc
    for (int i = tid; i < T; i += 512) {
        unsigned rec = raw_s[i];
        int ld = (int)(rec >> 16);
        int pos = atomicAdd(&cur_s[ld], 1);
        unsigned short sv = (unsigned short)(rec & 0xffffu);
        if (pos < 2048) {
            list_s[pos] = sv;
            sortedSrc[(b << CAPSH) + pos] = sv;
        }
    }
    __syncthreads();                                   // sync 5
    // agg phase: 8 lanes per node, indices from LDS (r10-r12 verified)
    int g = tid >> 3, l = tid & 7;
    int node = (b << BSH) + g;
    if (node >= N) return;
    int beg = off_s[g];
    int end = beg + cnt_s[g];
    float a0 = 0.f, a1 = 0.f, a2 = 0.f, a3 = 0.f,
          a4 = 0.f, a5 = 0.f, a6 = 0.f, a7 = 0.f;
    int i = beg;
    for (; i + 3 < end; i += 4) {
        uint2 idx = *(const uint2*)&list_s[i];        // 8 B aligned (pad4)
        int s0 = idx.x & 0xffffu, s1 = idx.x >> 16;
        int s2 = idx.y & 0xffffu, s3 = idx.y >> 16;
        uint4 u0 = t1v[s0 * 8 + l];
        uint4 u1 = t1v[s1 * 8 + l];
        uint4 u2 = t1v[s2 * 8 + l];
        uint4 u3 = t1v[s3 * 8 + l];
        a0 += bflo(u0.x) + bflo(u1.x) + bflo(u2.x) + bflo(u3.x);
        a1 += bfhi(u0.x) + bfhi(u1.x) + bfhi(u2.x) + bfhi(u3.x);
        a2 += bflo(u0.y) + bflo(u1.y) + bflo(u2.y) + bflo(u3.y);
        a3 += bfhi(u0.y) + bfhi(u1.y) + bfhi(u2.y) + bfhi(u3.y);
        a4 += bflo(u0.z) + bflo(u1.z) + bflo(u2.z) + bflo(u3.z);
        a5 += bfhi(u0.z) + bfhi(u1.z) + bfhi(u2.z) + bfhi(u3.z);
        a6 += bflo(u0.w) + bflo(u1.w) + bflo(u2.w) + bflo(u3.w);
        a7 += bfhi(u0.w) + bfhi(u1.w) + bfhi(u2.w) + bfhi(u3.w);
    }
    for (; i < end; ++i) {
        uint4 u = t1v[(int)list_s[i] * 8 + l];
        a0 += bflo(u.x); a1 += bfhi(u.x);
        a2 += bflo(u.y); a3 += bfhi(u.y);
        a4 += bflo(u.z); a5 += bfhi(u.z);
        a6 += bflo(u.w); a7 += bfhi(u.w);
    }
    int f0 = l * 8;
    unsigned tb = (unsigned)(node * HID + f0);
    float acc[8] = {a0, a1, a2, a3, a4, a5, a6, a7};
    float s0 = 0.f, s1 = 0.f, s2 = 0.f, s3 = 0.f, s4 = 0.f;
    #pragma unroll
    for (int j = 0; j < 8; ++j) {
        float h = fmaxf(acc[j] + sB1[f0 + j], 0.0f) * drop_mask_mul(tb + j);
        const float* w = &sW2[(f0 + j) * NCLS];
        s0 += h * w[0]; s1 += h * w[1]; s2 += h * w[2];
        s3 += h * w[3]; s4 += h * w[4];
    }
    #pragma unroll
    for (int off = 1; off < 8; off <<= 1) {
        s0 += __shfl_xor(s0, off);
        s1 += __shfl_xor(s1, off);
        s2 += __shfl_xor(s2, off);
        s3 += __shfl_xor(s3, off);
        s4 += __shfl_xor(s4, off);
    }
    float v = (l == 0) ? s0 : (l == 1) ? s1 : (l == 2) ? s2
             : (l == 3) ? s3 : s4;
    if (l < NCLS) t2p[node * 8 + l] = v;
}

// ====== kernel 3: layer-2 aggregate + bias (r10-r12 verified) ==============
__global__ __launch_bounds__(256) void out_fused_kernel(
        const int* __restrict__ offset, const int* __restrict__ count,
        const unsigned short* __restrict__ sortedSrc,
        const float* __restrict__ t2p, const float* __restrict__ b2,
        float* __restrict__ out, int N) {
    int tid = blockIdx.x * 256 + threadIdx.x;
    if (tid >= N * NCLS) return;
    int node = tid / NCLS;
    int c = tid - node * NCLS;
    int beg = offset[node];
    int end = beg + count[node];
    float accA = b2[c], accB = 0.f;
    int i = beg;
    for (; i + 3 < end; i += 4) {
        uint2 idx = *(const uint2*)&sortedSrc[i];
        int s0 = idx.x & 0xffffu, s1 = idx.x >> 16;
        int s2 = idx.y & 0xffffu, s3 = idx.y >> 16;
        accA += t2p[s0 * 8 + c] + t2p[s1 * 8 + c];
        accB += t2p[s2 * 8 + c] + t2p[s3 * 8 + c];
    }
    for (; i < end; ++i) accA += t2p[(int)sortedSrc[i] * 8 + c];
    out[tid] = accA + accB;
}

// ===========================================================================
extern "C" void kernel_launch(void* const* d_in, const int* in_sizes, int n_in,
                              void* d_out, int out_size, void* d_ws, size_t ws_size,
                              hipStream_t stream) {
    const float* x   = (const float*)d_in[0];
    const int*   ei  = (const int*)d_in[1];    // int32
    const float* W1  = (const float*)d_in[2];
    const float* b1  = (const float*)d_in[3];
    const float* W2  = (const float*)d_in[4];
    const float* b2  = (const float*)d_in[5];
    float*       out = (float*)d_out;

    const int N = in_sizes[0] / FIN;   // 50000
    const int E = in_sizes[1] / 2;     // 800000
    const int* src = ei;               // edge_index[0]
    const int* dst = ei + E;           // edge_index[1]

    const int NB  = (N + BNODES - 1) / BNODES;   // 782 buckets
    const int nbb = (E + EPB - 1) / EPB;         // 196 bin blocks
    const int g1b = (N + G1R - 1) / G1R;         // 782 gemm blocks

    // workspace (~17 MB)
    unsigned short* t1b       = (unsigned short*)d_ws;             // N*HID bf16
    float*          t2p       = (float*)(t1b + (size_t)N * HID);   // N*8 f32
    int*            count     = (int*)(t2p + (size_t)N * 8);       // N
    int*            offset    = count + N;                         // N
    int*            cntMat    = offset + N;                        // nbb*NB
    int*            startMat  = cntMat + (size_t)nbb * NB;         // nbb*NB
    unsigned*       bin       = (unsigned*)(startMat + (size_t)nbb * NB); // E
    unsigned short* sortedSrc = (unsigned short*)(bin + E);        // NB<<11

    gemm1_bin_kernel<<<nbb + g1b, 256, 0, stream>>>(
        x, W1, t1b, src, dst, cntMat, startMat, bin, N, E, NB, nbb);

    sortagg_kernel<<<NB, 512, 0, stream>>>(
        cntMat, startMat, bin, (const uint4*)t1b, b1, W2,
        offset, count, sortedSrc, t2p, N, nbb, NB);

    out_fused_kernel<<<(N * NCLS + 255) / 256, 256, 0, stream>>>(
        offset, count, sortedSrc, t2p, b2, out, N);
}

// Round 14
// 58.553 us; speedup vs baseline: 1.0054x; 1.0054x over previous
//
#include <hip/hip_runtime.h>

#define FIN 96
#define HID 64
#define NCLS 5
#define BSH 6                 // 64 nodes per coarse bucket
#define BNODES 64
#define MAXNB 1024            // >= NB = ceil(50000/64) = 782
#define CAPSH 11              // 2048-slot sortedSrc window per bucket
#define EPB 4096              // edges per bin block
#define MAXRUNS 256           // >= nbb = ceil(800000/4096) = 196
#define G1R 64                // gemm1 rows per block
#define SXP 100               // padded sX stride (floats)

// ---------------- threefry2x32 (JAX partitionable path, verified r3-r13) ---
__device__ __forceinline__ unsigned rotl32(unsigned x, int d) {
    return (x << d) | (x >> (32 - d));
}

__device__ __forceinline__ void threefry2x32(unsigned k0, unsigned k1,
                                             unsigned c0, unsigned c1,
                                             unsigned& o0, unsigned& o1) {
    unsigned ks2 = k0 ^ k1 ^ 0x1BD11BDAu;
    unsigned x0 = c0 + k0, x1 = c1 + k1;
#define RND(r) { x0 += x1; x1 = rotl32(x1, r); x1 ^= x0; }
#define G0 RND(13) RND(15) RND(26) RND(6)
#define G1 RND(17) RND(29) RND(16) RND(24)
    G0; x0 += k1;  x1 += ks2 + 1u;
    G1; x0 += ks2; x1 += k0 + 2u;
    G0; x0 += k0;  x1 += k1 + 3u;
    G1; x0 += k1;  x1 += ks2 + 4u;
    G0; x0 += ks2; x1 += k0 + 5u;
#undef G0
#undef G1
#undef RND
    o0 = x0; o1 = x1;
}

__device__ __forceinline__ float drop_mask_mul(unsigned t) {
    unsigned o0, o1;
    threefry2x32(0u, 1u, 0u, t, o0, o1);
    unsigned bits = o0 ^ o1;
    float u = __uint_as_float((bits >> 9) | 0x3f800000u) - 1.0f;
    return (u < 0.4f) ? 2.5f : 0.0f;   // 1/(1-0.6)
}

__device__ __forceinline__ unsigned short f2bf(float f) {
    unsigned u = __float_as_uint(f);
    unsigned r = 0x7fffu + ((u >> 16) & 1u);
    return (unsigned short)((u + r) >> 16);
}

__device__ __forceinline__ float bflo(unsigned u) { return __uint_as_float(u << 16); }
__device__ __forceinline__ float bfhi(unsigned u) { return __uint_as_float(u & 0xffff0000u); }

// single-wave exclusive scan of per-lane totals (lanes 0..63, no barriers)
__device__ __forceinline__ int wave_excl_scan(int v, int lane) {
    int inc = v;
    #pragma unroll
    for (int off = 1; off < 64; off <<= 1) {
        int u = __shfl_up(inc, off, 64);
        if (lane >= off) inc += u;
    }
    return inc - v;
}

// ====== kernel 1: bin blocks [0,nbb) || gemm1 blocks [nbb, nbb+g1b) ========
__global__ __launch_bounds__(256) void gemm1_bin_kernel(
        const float* __restrict__ x, const float* __restrict__ W,
        unsigned short* __restrict__ t1b,
        const int* __restrict__ src, const int* __restrict__ dst,
        int* __restrict__ cntMat, int* __restrict__ startMat,
        unsigned* __restrict__ bin, int N, int E, int NB, int nbb) {
    __shared__ __align__(16) char smem[50176];
    if ((int)blockIdx.x < nbb) {
        // ---------------- bin path: dense per-block bucket grouping --------
        int* hist_s = (int*)smem;            // [MAXNB]
        int* cur_s  = hist_s + MAXNB;        // [MAXNB]
        int blk = blockIdx.x;
        int e0 = blk * EPB;
        for (int k = threadIdx.x; k < NB; k += 256) hist_s[k] = 0;
        __syncthreads();
        int ss[16], dd[16];
        int base = e0 + threadIdx.x * 16;
        #pragma unroll
        for (int q = 0; q < 4; ++q) {
            int b4 = base + q * 4;
            if (b4 + 3 < E) {
                int4 s4 = *(const int4*)&src[b4];
                int4 d4 = *(const int4*)&dst[b4];
                ss[q*4+0]=s4.x; ss[q*4+1]=s4.y; ss[q*4+2]=s4.z; ss[q*4+3]=s4.w;
                dd[q*4+0]=d4.x; dd[q*4+1]=d4.y; dd[q*4+2]=d4.z; dd[q*4+3]=d4.w;
            } else {
                #pragma unroll
                for (int j = 0; j < 4; ++j) {
                    ss[q*4+j] = (b4+j < E) ? src[b4+j] : 0;
                    dd[q*4+j] = (b4+j < E) ? dst[b4+j] : -1;
                }
            }
        }
        #pragma unroll
        for (int j = 0; j < 16; ++j)
            if (dd[j] >= 0) atomicAdd(&hist_s[dd[j] >> BSH], 1);
        __syncthreads();
        // single-wave exclusive scan over NB buckets (13 entries/lane)
        if (threadIdx.x < 64) {
            int lane = threadIdx.x;
            int h[13]; int t = 0;
            #pragma unroll
            for (int j = 0; j < 13; ++j) {
                int k = lane * 13 + j;
                h[j] = (k < NB) ? hist_s[k] : 0;
                t += h[j];
            }
            int excl = wave_excl_scan(t, lane);
            #pragma unroll
            for (int j = 0; j < 13; ++j) {
                int k = lane * 13 + j;
                if (k < NB) {
                    cur_s[k] = excl;
                    cntMat[blk * NB + k]   = h[j];            // block-major
                    startMat[blk * NB + k] = e0 + excl;       // absolute
                }
                excl += h[j];
            }
        }
        __syncthreads();
        #pragma unroll
        for (int j = 0; j < 16; ++j) {
            int d = dd[j];
            if (d < 0) continue;
            int k = d >> BSH;
            int p = e0 + atomicAdd(&cur_s[k], 1);
            bin[p] = ((unsigned)(d & (BNODES - 1)) << 16) | (unsigned)ss[j];
        }
    } else {
        // ---------------- gemm1 path (r10-r13 verified, 4x4 reg tiling) ----
        float* sX = (float*)smem;                 // 64*100*4 = 25600 B
        float* sW = (float*)(smem + 25600);       // 96*64*4  = 24576 B
        int row0 = ((int)blockIdx.x - nbb) * G1R;
        for (int i = threadIdx.x * 4; i < FIN * HID; i += 1024)
            *(float4*)&sW[i] = *(const float4*)&W[i];
        for (int i = threadIdx.x; i < G1R * (FIN / 4); i += 256) {
            int r = i / (FIN / 4), m = i % (FIN / 4);
            int gr = row0 + r;
            float4 v = make_float4(0.f, 0.f, 0.f, 0.f);
            if (gr < N) v = *(const float4*)&x[gr * FIN + m * 4];
            *(float4*)&sX[r * SXP + m * 4] = v;
        }
        __syncthreads();
        int tc = threadIdx.x & 15;
        int tr = threadIdx.x >> 4;
        float acc[4][4] = {};
        const float* xb = &sX[tr * 4 * SXP];
        for (int k = 0; k < FIN; ++k) {
            float4 w = *(const float4*)&sW[k * HID + tc * 4];
            #pragma unroll
            for (int j = 0; j < 4; ++j) {
                float xv = xb[j * SXP + k];
                acc[j][0] += xv * w.x;
                acc[j][1] += xv * w.y;
                acc[j][2] += xv * w.z;
                acc[j][3] += xv * w.w;
            }
        }
        #pragma unroll
        for (int j = 0; j < 4; ++j) {
            int gr = row0 + tr * 4 + j;
            if (gr < N) {
                ushort4 o;
                o.x = f2bf(acc[j][0]); o.y = f2bf(acc[j][1]);
                o.z = f2bf(acc[j][2]); o.w = f2bf(acc[j][3]);
                *(ushort4*)&t1b[gr * HID + tc * 4] = o;
            }
        }
    }
}

// ====== kernel 2: per-bucket counting sort (LDS) + agg1 + gemm2 ===========
// 512 threads; agg phase = 64 nodes x 8 lanes; node segments padded to 8.
__global__ __launch_bounds__(512) void sortagg_kernel(
        const int* __restrict__ cntMat, const int* __restrict__ startMat,
        const unsigned* __restrict__ bin, const uint4* __restrict__ t1v,
        const float* __restrict__ b1, const float* __restrict__ W2,
        int* __restrict__ offset, int* __restrict__ count,
        unsigned short* __restrict__ sortedSrc, float* __restrict__ t2p,
        int N, int nbb, int NB) {
    __shared__ int cntRow[MAXRUNS];
    __shared__ int startRow[MAXRUNS];
    __shared__ int runOff[MAXRUNS + 1];
    __shared__ int cnt_s[BNODES], off_s[BNODES], cur_s[BNODES];
    __shared__ unsigned raw_s[2048];
    __shared__ __align__(16) unsigned short list_s[2048];
    __shared__ float sW2[HID * NCLS];
    __shared__ float sB1[HID];
    int b = blockIdx.x, tid = threadIdx.x;

    for (int i = tid; i < HID * NCLS; i += 512) sW2[i] = W2[i];
    if (tid < HID) sB1[tid] = b1[tid];
    if (tid < nbb) {
        cntRow[tid]   = cntMat[tid * NB + b];     // block-major source
        startRow[tid] = startMat[tid * NB + b];
    }
    if (tid < BNODES) cnt_s[tid] = 0;
    __syncthreads();                                   // sync 1
    // single-wave exclusive scan -> runOff[0..nbb] (4 entries/lane)
    if (tid < 64) {
        int c[4]; int t = 0;
        #pragma unroll
        for (int j = 0; j < 4; ++j) {
            int r = tid * 4 + j;
            c[j] = (r < nbb) ? cntRow[r] : 0;
            t += c[j];
        }
        int excl = wave_excl_scan(t, tid);
        #pragma unroll
        for (int j = 0; j < 4; ++j) {
            runOff[tid * 4 + j] = excl;
            excl += c[j];
        }
        if (tid == 63) runOff[256] = excl;             // unused guard
    }
    __syncthreads();                                   // sync 2
    int T = runOff[nbb];
    if (T > 2048) T = 2048;                            // safety (never hit)

    // pass 1: gather recs -> raw_s, node histogram
    for (int i = tid; i < T; i += 512) {
        int lo = 0, hi = nbb;
        while (hi - lo > 1) {
            int mid = (lo + hi) >> 1;
            if (runOff[mid] <= i) lo = mid; else hi = mid;
        }
        unsigned rec = bin[startRow[lo] + (i - runOff[lo])];
        raw_s[i] = rec;
        atomicAdd(&cnt_s[rec >> 16], 1);
    }
    __syncthreads();                                   // sync 3
    // single-wave pad8 exclusive scan over 64 node counts (1 entry/lane)
    if (tid < 64) {
        int c0 = cnt_s[tid];
        int p0 = (c0 + 7) & ~7;                        // pad8 (uint4 idx loads)
        int excl = wave_excl_scan(p0, tid);
        off_s[tid] = excl;
        cur_s[tid] = excl;
        int node = (b << BSH) + tid;
        if (node < N) {
            offset[node] = (b << CAPSH) + excl;
            count[node]  = c0;
        }
    }
    __syncthreads();                                   // sync 4
    // pass 2: scatter into node-grouped list (LDS) + global sortedSrc
    for (int i = tid; i < T; i += 512) {
        unsigned rec = raw_s[i];
        int ld = (int)(rec >> 16);
        int pos = atomicAdd(&cur_s[ld], 1);
        unsigned short sv = (unsigned short)(rec & 0xffffu);
        if (pos < 2048) {
            list_s[pos] = sv;
            sortedSrc[(b << CAPSH) + pos] = sv;
        }
    }
    __syncthreads();                                   // sync 5
    // agg phase: 8 lanes per node, 8-deep unrolled gather from LDS indices
    int g = tid >> 3, l = tid & 7;
    int node = (b << BSH) + g;
    if (node >= N) return;
    int beg = off_s[g];
    int end = beg + cnt_s[g];
    float a0 = 0.f, a1 = 0.f, a2 = 0.f, a3 = 0.f,
          a4 = 0.f, a5 = 0.f, a6 = 0.f, a7 = 0.f;
    int i = beg;
    for (; i + 7 < end; i += 8) {                      // 16B-aligned (pad8)
        uint4 idx = *(const uint4*)&list_s[i];         // 8 indices at once
        int s0 = idx.x & 0xffffu, s1 = idx.x >> 16;
        int s2 = idx.y & 0xffffu, s3 = idx.y >> 16;
        int s4 = idx.z & 0xffffu, s5 = idx.z >> 16;
        int s6 = idx.w & 0xffffu, s7 = idx.w >> 16;
        uint4 u0 = t1v[s0 * 8 + l];
        uint4 u1 = t1v[s1 * 8 + l];
        uint4 u2 = t1v[s2 * 8 + l];
        uint4 u3 = t1v[s3 * 8 + l];
        uint4 u4 = t1v[s4 * 8 + l];
        uint4 u5 = t1v[s5 * 8 + l];
        uint4 u6 = t1v[s6 * 8 + l];
        uint4 u7 = t1v[s7 * 8 + l];
        a0 += bflo(u0.x) + bflo(u1.x) + bflo(u2.x) + bflo(u3.x)
            + bflo(u4.x) + bflo(u5.x) + bflo(u6.x) + bflo(u7.x);
        a1 += bfhi(u0.x) + bfhi(u1.x) + bfhi(u2.x) + bfhi(u3.x)
            + bfhi(u4.x) + bfhi(u5.x) + bfhi(u6.x) + bfhi(u7.x);
        a2 += bflo(u0.y) + bflo(u1.y) + bflo(u2.y) + bflo(u3.y)
            + bflo(u4.y) + bflo(u5.y) + bflo(u6.y) + bflo(u7.y);
        a3 += bfhi(u0.y) + bfhi(u1.y) + bfhi(u2.y) + bfhi(u3.y)
            + bfhi(u4.y) + bfhi(u5.y) + bfhi(u6.y) + bfhi(u7.y);
        a4 += bflo(u0.z) + bflo(u1.z) + bflo(u2.z) + bflo(u3.z)
            + bflo(u4.z) + bflo(u5.z) + bflo(u6.z) + bflo(u7.z);
        a5 += bfhi(u0.z) + bfhi(u1.z) + bfhi(u2.z) + bfhi(u3.z)
            + bfhi(u4.z) + bfhi(u5.z) + bfhi(u6.z) + bfhi(u7.z);
        a6 += bflo(u0.w) + bflo(u1.w) + bflo(u2.w) + bflo(u3.w)
            + bflo(u4.w) + bflo(u5.w) + bflo(u6.w) + bflo(u7.w);
        a7 += bfhi(u0.w) + bfhi(u1.w) + bfhi(u2.w) + bfhi(u3.w)
            + bfhi(u4.w) + bfhi(u5.w) + bfhi(u6.w) + bfhi(u7.w);
    }
    for (; i + 3 < end; i += 4) {
        uint2 idx = *(const uint2*)&list_s[i];
        int s0 = idx.x & 0xffffu, s1 = idx.x >> 16;
        int s2 = idx.y & 0xffffu, s3 = idx.y >> 16;
        uint4 u0 = t1v[s0 * 8 + l];
        uint4 u1 = t1v[s1 * 8 + l];
        uint4 u2 = t1v[s2 * 8 + l];
        uint4 u3 = t1v[s3 * 8 + l];
        a0 += bflo(u0.x) + bflo(u1.x) + bflo(u2.x) + bflo(u3.x);
        a1 += bfhi(u0.x) + bfhi(u1.x) + bfhi(u2.x) + bfhi(u3.x);
        a2 += bflo(u0.y) + bflo(u1.y) + bflo(u2.y) + bflo(u3.y);
        a3 += bfhi(u0.y) + bfhi(u1.y) + bfhi(u2.y) + bfhi(u3.y);
        a4 += bflo(u0.z) + bflo(u1.z) + bflo(u2.z) + bflo(u3.z);
        a5 += bfhi(u0.z) + bfhi(u1.z) + bfhi(u2.z) + bfhi(u3.z);
        a6 += bflo(u0.w) + bflo(u1.w) + bflo(u2.w) + bflo(u3.w);
        a7 += bfhi(u0.w) + bfhi(u1.w) + bfhi(u2.w) + bfhi(u3.w);
    }
    for (; i < end; ++i) {
        uint4 u = t1v[(int)list_s[i] * 8 + l];
        a0 += bflo(u.x); a1 += bfhi(u.x);
        a2 += bflo(u.y); a3 += bfhi(u.y);
        a4 += bflo(u.z); a5 += bfhi(u.z);
        a6 += bflo(u.w); a7 += bfhi(u.w);
    }
    int f0 = l * 8;
    unsigned tb = (unsigned)(node * HID + f0);
    float acc[8] = {a0, a1, a2, a3, a4, a5, a6, a7};
    float s0 = 0.f, s1 = 0.f, s2 = 0.f, s3 = 0.f, s4 = 0.f;
    #pragma unroll
    for (int j = 0; j < 8; ++j) {
        float h = fmaxf(acc[j] + sB1[f0 + j], 0.0f) * drop_mask_mul(tb + j);
        const float* w = &sW2[(f0 + j) * NCLS];
        s0 += h * w[0]; s1 += h * w[1]; s2 += h * w[2];
        s3 += h * w[3]; s4 += h * w[4];
    }
    #pragma unroll
    for (int off = 1; off < 8; off <<= 1) {
        s0 += __shfl_xor(s0, off);
        s1 += __shfl_xor(s1, off);
        s2 += __shfl_xor(s2, off);
        s3 += __shfl_xor(s3, off);
        s4 += __shfl_xor(s4, off);
    }
    float v = (l == 0) ? s0 : (l == 1) ? s1 : (l == 2) ? s2
             : (l == 3) ? s3 : s4;
    if (l < NCLS) t2p[node * 8 + l] = v;
}

// ====== kernel 3: layer-2 aggregate + bias (4 lanes/node, row loads) =======
__global__ __launch_bounds__(256) void out_fused_kernel(
        const int* __restrict__ offset, const int* __restrict__ count,
        const unsigned short* __restrict__ sortedSrc,
        const float* __restrict__ t2p, const float* __restrict__ b2,
        float* __restrict__ out, int N) {
    int tid = blockIdx.x * 256 + threadIdx.x;
    int node = tid >> 2;
    int l = tid & 3;
    if (node >= N) return;
    int beg = offset[node];
    int end = beg + count[node];
    float s0 = 0.f, s1 = 0.f, s2 = 0.f, s3 = 0.f, s4 = 0.f;
    int i = beg + l;
    for (; i + 4 < end; i += 8) {                 // 2 edge-rows in flight
        int sa = sortedSrc[i];
        int sb = sortedSrc[i + 4];
        float4 va = *(const float4*)&t2p[sa * 8];
        float  wa = t2p[sa * 8 + 4];
        float4 vb = *(const float4*)&t2p[sb * 8];
        float  wb = t2p[sb * 8 + 4];
        s0 += va.x + vb.x; s1 += va.y + vb.y; s2 += va.z + vb.z;
        s3 += va.w + vb.w; s4 += wa + wb;
    }
    if (i < end) {
        int sa = sortedSrc[i];
        float4 va = *(const float4*)&t2p[sa * 8];
        s0 += va.x; s1 += va.y; s2 += va.z; s3 += va.w;
        s4 += t2p[sa * 8 + 4];
    }
    #pragma unroll
    for (int off = 1; off < 4; off <<= 1) {       // 4-lane butterfly
        s0 += __shfl_xor(s0, off, 4);
        s1 += __shfl_xor(s1, off, 4);
        s2 += __shfl_xor(s2, off, 4);
        s3 += __shfl_xor(s3, off, 4);
        s4 += __shfl_xor(s4, off, 4);
    }
    float v = (l == 0) ? s0 : (l == 1) ? s1 : (l == 2) ? s2 : s3;
    out[node * NCLS + l] = v + b2[l];
    if (l == 0) out[node * NCLS + 4] = s4 + b2[4];
}

// ===========================================================================
extern "C" void kernel_launch(void* const* d_in, const int* in_sizes, int n_in,
                              void* d_out, int out_size, void* d_ws, size_t ws_size,
                              hipStream_t stream) {
    const float* x   = (const float*)d_in[0];
    const int*   ei  = (const int*)d_in[1];    // int32
    const float* W1  = (const float*)d_in[2];
    const float* b1  = (const float*)d_in[3];
    const float* W2  = (const float*)d_in[4];
    const float* b2  = (const float*)d_in[5];
    float*       out = (float*)d_out;

    const int N = in_sizes[0] / FIN;   // 50000
    const int E = in_sizes[1] / 2;     // 800000
    const int* src = ei;               // edge_index[0]
    const int* dst = ei + E;           // edge_index[1]

    const int NB  = (N + BNODES - 1) / BNODES;   // 782 buckets
    const int nbb = (E + EPB - 1) / EPB;         // 196 bin blocks
    const int g1b = (N + G1R - 1) / G1R;         // 782 gemm blocks

    // workspace (~17 MB)
    unsigned short* t1b       = (unsigned short*)d_ws;             // N*HID bf16
    float*          t2p       = (float*)(t1b + (size_t)N * HID);   // N*8 f32
    int*            count     = (int*)(t2p + (size_t)N * 8);       // N
    int*            offset    = count + N;                         // N
    int*            cntMat    = offset + N;                        // nbb*NB
    int*            startMat  = cntMat + (size_t)nbb * NB;         // nbb*NB
    unsigned*       bin       = (unsigned*)(startMat + (size_t)nbb * NB); // E
    unsigned short* sortedSrc = (unsigned short*)(bin + E);        // NB<<11

    gemm1_bin_kernel<<<nbb + g1b, 256, 0, stream>>>(
        x, W1, t1b, src, dst, cntMat, startMat, bin, N, E, NB, nbb);

    sortagg_kernel<<<NB, 512, 0, stream>>>(
        cntMat, startMat, bin, (const uint4*)t1b, b1, W2,
        offset, count, sortedSrc, t2p, N, nbb, NB);

    out_fused_kernel<<<(N * 4 + 255) / 256, 256, 0, stream>>>(
        offset, count, sortedSrc, t2p, b2, out, N);
}